// Round 4
// baseline (112.694 us; speedup 1.0000x reference)
//
#include <hip/hip_runtime.h>
#include <hip/hip_bf16.h>
#include <math.h>

#define BSZ 4096
#define DIM 768
#define BK 64
#define NTILE (DIM / BK)     // 12 K-tiles
#define CSPLIT 16            // 4096/256 column panels

typedef __attribute__((ext_vector_type(8))) short short8;
typedef __attribute__((ext_vector_type(4))) float f32x4;

__device__ __forceinline__ unsigned short f2bf(float f) {
  unsigned u = __float_as_uint(f);
  u += 0x7fffu + ((u >> 16) & 1u);   // RNE
  return (unsigned short)(u >> 16);
}

__device__ __forceinline__ short8 lds_ld(const unsigned char* p) {
  return *(const short8*)p;
}

// convert 8 fp32 -> 8 bf16, one ds_write_b128
__device__ __forceinline__ void cvt_write(unsigned char* dst, f32x4 a, f32x4 b) {
  short8 o;
  o[0] = (short)f2bf(a[0]); o[1] = (short)f2bf(a[1]);
  o[2] = (short)f2bf(a[2]); o[3] = (short)f2bf(a[3]);
  o[4] = (short)f2bf(b[0]); o[5] = (short)f2bf(b[1]);
  o[6] = (short)f2bf(b[2]); o[7] = (short)f2bf(b[3]);
  *(short8*)dst = o;
}

// device-coherent (agent-scope, L2-bypassing) accessors — NO whole-L2 fences
__device__ __forceinline__ void cstore(float* p, float v) {
  __hip_atomic_store(p, v, __ATOMIC_RELAXED, __HIP_MEMORY_SCOPE_AGENT);
}
__device__ __forceinline__ float cload(const float* p) {
  return __hip_atomic_load(p, __ATOMIC_RELAXED, __HIP_MEMORY_SCOPE_AGENT);
}

// ---------------- fused convert + 256x256 GEMM + per-row LSE (m201-style) ----
// scores[i][j] = <nl[i], code[j]>. A = nl (rows), B = code (cols), both fp32.
// T14 fused staging: phase 0 issues 8 f32x4 B-loads (next tile), phase 1 the
// 8 A-loads; phase 2 converts+ds_writes B, phase 3 A. Compiler emits counted
// vmcnt for the register loads (B drain = vmcnt(8), A = vmcnt(0)).
// LDS layout/swizzle and MFMA read path identical to the gload_lds version:
// LDS block b of row r holds global 8-elem block (b ^ (r&7)).
// Cross-block LSE merge via agent-scope sc1 stores/loads (no __threadfence).
__global__ __launch_bounds__(512, 2)
void gemm_lse_kernel(const float* __restrict__ Af,   // nl   [BSZ][DIM] fp32
                     const float* __restrict__ Bf,   // code [BSZ][DIM] fp32
                     float* __restrict__ pm, float* __restrict__ ps,
                     float* __restrict__ diag,
                     float* __restrict__ partial,
                     unsigned int* __restrict__ cnt,
                     float* __restrict__ out)
{
  __shared__ alignas(16) unsigned char smem[131072];
  // bufA[c] @ c*32768 (256 rows x 128B); bufB[c] @ 65536 + c*32768
  const int tid  = threadIdx.x;
  const int w    = tid >> 6;
  const int lane = tid & 63;
  const int lr   = lane & 15;
  const int hi   = lane >> 4;
  const int wm   = w >> 2;
  const int wn   = w & 3;

  // bijective XCD swizzle: 8 XCDs each own a 4x8 sub-grid (256 % 8 == 0)
  const int id  = blockIdx.y * 16 + blockIdx.x;   // hw dispatch order, x fastest
  const int xcd = id & 7, sq = id >> 3;
  const int bx  = ((xcd & 3) << 2) | (sq & 3);    // row panel   [0,16)
  const int by  = ((xcd >> 2) << 3) | (sq >> 2);  // col panel   [0,16)
  const int i0 = bx << 8;
  const int j0 = by << 8;

  // swizzled 16B-block byte offset within a 128B row (row&7 == lr&7 for frag rows)
  const int fb0 = (hi ^ (lr & 7)) << 4;          // k-chunk 0
  const int fb1 = ((4 + hi) ^ (lr & 7)) << 4;    // k-chunk 1
  const int arowb = (wm * 128 + lr) * 128;       // + m*2048
  const int browb = (wn * 64 + lr) * 128;        // + n*2048

  // staging: thread t covers row srow (per 64-row chunk q), 8-elem block seg
  const int srow = tid >> 3;                     // 0..63
  const int seg  = tid & 7;                      // global 8-elem block
  const float* gA = Af + (size_t)(i0 + srow) * DIM + (seg << 3);
  const float* gB = Bf + (size_t)(j0 + srow) * DIM + (seg << 3);
  // LDS byte offset within a 8 KB chunk: swizzled dest block = seg ^ (srow&7)
  const int swz = srow * 128 + ((seg ^ (srow & 7)) << 4);

  f32x4 acc[8][4];
#pragma unroll
  for (int m = 0; m < 8; ++m)
#pragma unroll
    for (int n = 0; n < 4; ++n)
      acc[m][n] = (f32x4){0.f, 0.f, 0.f, 0.f};

  f32x4 ar[8], br[8];

  // prologue: load+convert+stage tile 0 into buffer 0
#pragma unroll
  for (int q = 0; q < 4; ++q)
#pragma unroll
    for (int h = 0; h < 2; ++h) {
      br[q * 2 + h] = *reinterpret_cast<const f32x4*>(gB + (size_t)(q * 64) * DIM + h * 4);
      ar[q * 2 + h] = *reinterpret_cast<const f32x4*>(gA + (size_t)(q * 64) * DIM + h * 4);
    }
#pragma unroll
  for (int q = 0; q < 4; ++q) {
    cvt_write(smem + 65536 + q * 8192 + swz, br[2 * q], br[2 * q + 1]);
    cvt_write(smem +         q * 8192 + swz, ar[2 * q], ar[2 * q + 1]);
  }
  asm volatile("s_waitcnt lgkmcnt(0)" ::: "memory");
  __builtin_amdgcn_s_barrier();

#pragma unroll 2
  for (int u = 0; u < NTILE; ++u) {
    const int c = u & 1;
    const unsigned char* la = smem + c * 32768;
    const unsigned char* lb = smem + 65536 + c * 32768;
    unsigned char* na = smem + (c ^ 1) * 32768;
    unsigned char* nb = smem + 65536 + (c ^ 1) * 32768;
    const bool st = (u + 1 < NTILE);
    const size_t kn = (size_t)(u + 1) * BK;   // next tile's K offset (elements)

    short8 aF[4], bF[4];

    // ---------------- phase 0: m-half 0, k-chunk 0 ----------------
#pragma unroll
    for (int n = 0; n < 4; ++n) bF[n] = lds_ld(lb + browb + n * 2048 + fb0);
#pragma unroll
    for (int m = 0; m < 4; ++m) aF[m] = lds_ld(la + arowb + m * 2048 + fb0);
    if (st) {   // issue B(u+1) loads — consumed in phase 2
#pragma unroll
      for (int q = 0; q < 4; ++q)
#pragma unroll
        for (int h = 0; h < 2; ++h)
          br[q * 2 + h] = *reinterpret_cast<const f32x4*>(gB + (size_t)(q * 64) * DIM + kn + h * 4);
    }
    __builtin_amdgcn_s_barrier();
    asm volatile("s_waitcnt lgkmcnt(0)" ::: "memory");
    __builtin_amdgcn_s_setprio(1);
#pragma unroll
    for (int m = 0; m < 4; ++m)
#pragma unroll
      for (int n = 0; n < 4; ++n)
        acc[m][n] = __builtin_amdgcn_mfma_f32_16x16x32_bf16(aF[m], bF[n], acc[m][n], 0, 0, 0);
    __builtin_amdgcn_s_setprio(0);
    __builtin_amdgcn_s_barrier();

    // ---------------- phase 1: m-half 1, k-chunk 0 ----------------
#pragma unroll
    for (int m = 0; m < 4; ++m) aF[m] = lds_ld(la + arowb + (4 + m) * 2048 + fb0);
    if (st) {   // issue A(u+1) loads — consumed in phase 3
#pragma unroll
      for (int q = 0; q < 4; ++q)
#pragma unroll
        for (int h = 0; h < 2; ++h)
          ar[q * 2 + h] = *reinterpret_cast<const f32x4*>(gA + (size_t)(q * 64) * DIM + kn + h * 4);
    }
    __builtin_amdgcn_s_barrier();
    asm volatile("s_waitcnt lgkmcnt(0)" ::: "memory");
    __builtin_amdgcn_s_setprio(1);
#pragma unroll
    for (int m = 0; m < 4; ++m)
#pragma unroll
      for (int n = 0; n < 4; ++n)
        acc[4 + m][n] = __builtin_amdgcn_mfma_f32_16x16x32_bf16(aF[m], bF[n], acc[4 + m][n], 0, 0, 0);
    __builtin_amdgcn_s_setprio(0);
    __builtin_amdgcn_s_barrier();

    // ---------------- phase 2: m-half 0, k-chunk 1 ----------------
#pragma unroll
    for (int n = 0; n < 4; ++n) bF[n] = lds_ld(lb + browb + n * 2048 + fb1);
#pragma unroll
    for (int m = 0; m < 4; ++m) aF[m] = lds_ld(la + arowb + m * 2048 + fb1);
    __builtin_amdgcn_s_barrier();
    asm volatile("s_waitcnt lgkmcnt(0)" ::: "memory");
    __builtin_amdgcn_s_setprio(1);
#pragma unroll
    for (int m = 0; m < 4; ++m)
#pragma unroll
      for (int n = 0; n < 4; ++n)
        acc[m][n] = __builtin_amdgcn_mfma_f32_16x16x32_bf16(aF[m], bF[n], acc[m][n], 0, 0, 0);
    __builtin_amdgcn_s_setprio(0);
    if (st) {   // convert + stage B(u+1) (compiler waits vmcnt(8): A still out)
#pragma unroll
      for (int q = 0; q < 4; ++q)
        cvt_write(nb + q * 8192 + swz, br[2 * q], br[2 * q + 1]);
    }
    __builtin_amdgcn_s_barrier();

    // ---------------- phase 3: m-half 1, k-chunk 1 ----------------
#pragma unroll
    for (int m = 0; m < 4; ++m) aF[m] = lds_ld(la + arowb + (4 + m) * 2048 + fb1);
    __builtin_amdgcn_s_barrier();
    asm volatile("s_waitcnt lgkmcnt(0)" ::: "memory");
    __builtin_amdgcn_s_setprio(1);
#pragma unroll
    for (int m = 0; m < 4; ++m)
#pragma unroll
      for (int n = 0; n < 4; ++n)
        acc[4 + m][n] = __builtin_amdgcn_mfma_f32_16x16x32_bf16(aF[m], bF[n], acc[4 + m][n], 0, 0, 0);
    __builtin_amdgcn_s_setprio(0);
    if (st) {   // convert + stage A(u+1) (compiler waits vmcnt(0))
#pragma unroll
      for (int q = 0; q < 4; ++q)
        cvt_write(na + q * 8192 + swz, ar[2 * q], ar[2 * q + 1]);
    }
    asm volatile("s_waitcnt lgkmcnt(0)" ::: "memory");   // writes visible pre-barrier
    __builtin_amdgcn_s_barrier();
  }

  // ---------------- epilogue: diag + per-row LSE partials ----------------
  __syncthreads();

  if (i0 == j0) {
#pragma unroll
    for (int m = 0; m < 8; ++m)
#pragma unroll
      for (int n = 0; n < 4; ++n)
#pragma unroll
        for (int rr = 0; rr < 4; ++rr) {
          const int rl = wm * 128 + m * 16 + (hi << 2) + rr;
          const int cl = wn * 64 + n * 16 + lr;
          if (rl == cl) cstore(&diag[i0 + rl], acc[m][n][rr]);
        }
  }

  float* redm = (float*)smem;            // [4][256]
  float* reds = (float*)(smem + 4096);   // [4][256]

#pragma unroll
  for (int m = 0; m < 8; ++m) {
    float mx[4], sm[4];
#pragma unroll
    for (int rr = 0; rr < 4; ++rr) {
      float v = fmaxf(fmaxf(acc[m][0][rr], acc[m][1][rr]),
                      fmaxf(acc[m][2][rr], acc[m][3][rr]));
      mx[rr] = v;
    }
#pragma unroll
    for (int sh = 1; sh < 16; sh <<= 1)
#pragma unroll
      for (int rr = 0; rr < 4; ++rr)
        mx[rr] = fmaxf(mx[rr], __shfl_xor(mx[rr], sh, 64));
#pragma unroll
    for (int rr = 0; rr < 4; ++rr) {
      float s = 0.f;
#pragma unroll
      for (int n = 0; n < 4; ++n) s += __expf(acc[m][n][rr] - mx[rr]);
      sm[rr] = s;
    }
#pragma unroll
    for (int sh = 1; sh < 16; sh <<= 1)
#pragma unroll
      for (int rr = 0; rr < 4; ++rr)
        sm[rr] += __shfl_xor(sm[rr], sh, 64);
    if (lr == 0) {
#pragma unroll
      for (int rr = 0; rr < 4; ++rr) {
        const int rl = wm * 128 + m * 16 + (hi << 2) + rr;
        redm[(wn << 8) + rl] = mx[rr];
        reds[(wn << 8) + rl] = sm[rr];
      }
    }
  }
  __syncthreads();

  if (tid < 256) {
    float m = redm[tid];
#pragma unroll
    for (int v = 1; v < 4; ++v) m = fmaxf(m, redm[(v << 8) + tid]);
    float s = 0.f;
#pragma unroll
    for (int v = 0; v < 4; ++v) s += reds[(v << 8) + tid] * __expf(redm[(v << 8) + tid] - m);
    cstore(&pm[(size_t)by * BSZ + i0 + tid], m);
    cstore(&ps[(size_t)by * BSZ + i0 + tid], s);
  }

  // ---------------- cross-block merge (split-K last-block-wins) ----------------
  // All communicated stores above are sc1 (agent-coherent, past the XCD L2).
  // Each wave drains its own stores (vmcnt(0)), barrier, then one relaxed bump.
  asm volatile("s_waitcnt vmcnt(0)" ::: "memory");
  __syncthreads();
  __shared__ unsigned int sord;
  if (tid == 0) sord = atomicAdd(&cnt[bx], 1u);
  __syncthreads();
  if (sord == CSPLIT - 1) {
    float val = 0.f;
    if (tid < 256) {
      const int row = i0 + tid;
      float mv[CSPLIT];
      float m = -INFINITY;
#pragma unroll
      for (int c = 0; c < CSPLIT; ++c) {
        mv[c] = cload(&pm[(size_t)c * BSZ + row]);
        m = fmaxf(m, mv[c]);
      }
      float s = 0.f;
#pragma unroll
      for (int c = 0; c < CSPLIT; ++c)
        s += cload(&ps[(size_t)c * BSZ + row]) * __expf(mv[c] - m);
      val = (m + __logf(s)) - cload(&diag[row]);
    }
    float* red2 = (float*)smem;   // [512]; prior smem uses are done (synced above)
    red2[tid] = val;
    __syncthreads();
    for (int off = 256; off > 0; off >>= 1) {
      if (tid < off) red2[tid] += red2[tid + off];
      __syncthreads();
    }
    if (tid == 0) {
      cstore(&partial[bx], red2[0]);
      asm volatile("s_waitcnt vmcnt(0)" ::: "memory");
      unsigned int d = atomicAdd(&cnt[CSPLIT], 1u);
      if (d == CSPLIT - 1) {
        float s = 0.f;
        for (int i = 0; i < CSPLIT; ++i) s += cload(&partial[i]);
        out[0] = s / (float)BSZ;
      }
    }
  }
}

extern "C" void kernel_launch(void* const* d_in, const int* in_sizes, int n_in,
                              void* d_out, int out_size, void* d_ws, size_t ws_size,
                              hipStream_t stream) {
  const float* code = (const float*)d_in[0];   // [BSZ][DIM]
  const float* nl   = (const float*)d_in[1];   // [BSZ][DIM]
  float* out = (float*)d_out;

  char* ws = (char*)d_ws;
  float* pm   = (float*)ws;                                // [CSPLIT][BSZ]
  float* ps   = pm + (size_t)CSPLIT * BSZ;
  float* diag = ps + (size_t)CSPLIT * BSZ;                 // [BSZ]
  float* partial = diag + BSZ;                             // [16]
  unsigned int* cnt = (unsigned int*)(partial + CSPLIT);   // [17]

  hipMemsetAsync(cnt, 0, (CSPLIT + 1) * sizeof(unsigned int), stream);

  dim3 grid(BSZ / 256, BSZ / 256);
  gemm_lse_kernel<<<grid, 512, 0, stream>>>(nl, code, pm, ps, diag, partial, cnt, out);
}

// Round 5
// 52.255 us; speedup vs baseline: 2.1566x; 2.1566x over previous
//
#include <hip/hip_runtime.h>
#include <hip/hip_bf16.h>
#include <math.h>

#define BSZ 4096
#define DIM 768
#define BK 64
#define NTILE (DIM / BK)     // 12 K-tiles
#define CSPLIT 16            // 4096/256 column panels (by)
#define NPANEL 32            // 4096/128 row panels (bx)

typedef __attribute__((ext_vector_type(8))) short short8;
typedef __attribute__((ext_vector_type(4))) float f32x4;

__device__ __forceinline__ unsigned short f2bf(float f) {
  unsigned u = __float_as_uint(f);
  u += 0x7fffu + ((u >> 16) & 1u);   // RNE
  return (unsigned short)(u >> 16);
}

__device__ __forceinline__ void gload16(const void* gp, const void* lp) {
  __builtin_amdgcn_global_load_lds(
      (const __attribute__((address_space(1))) unsigned int*)(size_t)gp,
      (__attribute__((address_space(3))) unsigned int*)(unsigned int)(size_t)lp,
      16, 0, 0);
}

__device__ __forceinline__ short8 lds_ld(const unsigned char* p) {
  return *(const short8*)p;
}

// device-coherent (agent-scope, L2-bypassing) accessors — NO whole-L2 fences
__device__ __forceinline__ void cstore(float* p, float v) {
  __hip_atomic_store(p, v, __ATOMIC_RELAXED, __HIP_MEMORY_SCOPE_AGENT);
}
__device__ __forceinline__ float cload(const float* p) {
  return __hip_atomic_load(p, __ATOMIC_RELAXED, __HIP_MEMORY_SCOPE_AGENT);
}

// ---------------- fp32 -> bf16 conversion (both matrices) + counter init ----
__global__ void convert_kernel(const float* __restrict__ src0,   // nl
                               const float* __restrict__ src1,   // code
                               unsigned short* __restrict__ dst0,
                               unsigned short* __restrict__ dst1,
                               unsigned int* __restrict__ cnt)
{
  if (blockIdx.x == 0 && threadIdx.x <= NPANEL) cnt[threadIdx.x] = 0u;
  const int n4 = (BSZ * DIM) / 4;
  int i = blockIdx.x * blockDim.x + threadIdx.x;
  const float* src;
  unsigned short* dst;
  if (i < n4) { src = src0; dst = dst0; }
  else        { src = src1; dst = dst1; i -= n4; }
  float4 v = *reinterpret_cast<const float4*>(src + (size_t)i * 4);
  ushort4 o;
  o.x = f2bf(v.x); o.y = f2bf(v.y); o.z = f2bf(v.z); o.w = f2bf(v.w);
  *reinterpret_cast<ushort4*>(dst + (size_t)i * 4) = o;
}

// ---------------- fused 128x256 GEMM + per-row LSE partials ----------------
// scores[i][j] = <nl[i], code[j]>. A = nl (rows), B = code (cols).
// Tile 128x256, 8 waves = 2M x 4N; wave (wm,wn) owns rows [wm*64,+64) x
// cols [wn*64,+64); acc[4][4] (64 AGPRs). BK=64, 2 phases/K-tile x 16 MFMA,
// LDS 96KB dbuf (A 2x16KB, B 2x32KB), XOR(row&7) both-sides swizzle.
// L2-locality: XCD-chunked swizzle — each XCD owns an 8bx x 8by region,
// processed as 2 rounds of 8x4; concurrent working set 3.1MB <= 4MB XCD L2,
// round 2 reuses the A-panels. (256^2 tiles could not fit: >=4.7MB.)
// Cross-block LSE merge via agent-scope sc1 stores/loads (no __threadfence).
__global__ __launch_bounds__(512, 2)
void gemm_lse_kernel(const unsigned short* __restrict__ A,
                     const unsigned short* __restrict__ B,
                     float* __restrict__ pm, float* __restrict__ ps,
                     float* __restrict__ diag,
                     float* __restrict__ partial,
                     unsigned int* __restrict__ cnt,
                     float* __restrict__ out)
{
  __shared__ alignas(16) unsigned char smem[98304];
  // bufA[c] @ c*16384 (128 rows x 128B); bufB[c] @ 32768 + c*32768 (256 x 128B)
  const int tid  = threadIdx.x;
  const int w    = tid >> 6;
  const int lane = tid & 63;
  const int lr   = lane & 15;
  const int hi   = lane >> 4;
  const int wm   = w >> 2;
  const int wn   = w & 3;

  // XCD-chunked bijective swizzle: grid 32x16; XCD x owns bx in [ (x&3)*8,+8 ),
  // by in [ (x>>2)*8,+8 ), split into 2 rounds of 8bx x 4by.
  const int g   = blockIdx.y * 32 + blockIdx.x;   // hw dispatch order, x fastest
  const int xcd = g & 7;
  const int t   = g >> 3;          // 0..63 per XCD
  const int rnd = t >> 5;          // 0..1 (round)
  const int s   = t & 31;
  const int bxl = s & 7, byl = s >> 3;
  const int bx  = ((xcd & 3) << 3) | bxl;                 // 0..31
  const int by  = ((xcd >> 2) << 3) | (rnd << 2) | byl;   // 0..15
  const int i0  = bx << 7;    // row base (128-row panel)
  const int j0  = by << 8;    // col base (256-col panel)

  // swizzled 16B-block byte offset within a 128B row (row&7 == lr&7 for frag rows)
  const int fb0 = (hi ^ (lr & 7)) << 4;          // k-chunk 0
  const int fb1 = ((4 + hi) ^ (lr & 7)) << 4;    // k-chunk 1
  const int arowb = (wm * 64 + lr) * 128;        // + m*2048
  const int browb = (wn * 64 + lr) * 128;        // + n*2048

  // staging: thread t covers row srow (per 64-row chunk q) at swizzled block
  const int srow = tid >> 3;                               // 0..63
  const int gcol = ((tid & 7) ^ (srow & 7)) << 3;          // element col
  const unsigned short* pA = A + (size_t)(i0 + srow) * DIM + gcol;
  const unsigned short* pB = B + (size_t)(j0 + srow) * DIM + gcol;
  const int ldsbase = w << 10;   // wave-uniform; +q*8192; lane*16 added by HW

  f32x4 acc[4][4];
#pragma unroll
  for (int m = 0; m < 4; ++m)
#pragma unroll
    for (int n = 0; n < 4; ++n)
      acc[m][n] = (f32x4){0.f, 0.f, 0.f, 0.f};

  // prologue: stage tile 0 into buffer 0 (A: 2 chunks, B: 4 chunks)
  gload16(pA,                      smem +        ldsbase);
  gload16(pA + (size_t)64 * DIM,   smem + 8192 + ldsbase);
#pragma unroll
  for (int q = 0; q < 4; ++q)
    gload16(pB + (size_t)(q * 64) * DIM, smem + 32768 + q * 8192 + ldsbase);
  asm volatile("s_waitcnt vmcnt(0)" ::: "memory");
  __builtin_amdgcn_s_barrier();

#pragma unroll 2
  for (int u = 0; u < NTILE; ++u) {
    const int c = u & 1;
    const unsigned char* la = smem + c * 16384;
    const unsigned char* lb = smem + 32768 + c * 32768;
    unsigned char* na = smem + (c ^ 1) * 16384;
    unsigned char* nb = smem + 32768 + (c ^ 1) * 32768;
    const bool st = (u + 1 < NTILE);
    const size_t kn = (size_t)(u + 1) * BK;   // next tile's K offset (elements)

    short8 aF[4], bF[4];

    // ---------------- phase 0: k-chunk 0 ----------------
#pragma unroll
    for (int n = 0; n < 4; ++n) bF[n] = lds_ld(lb + browb + n * 2048 + fb0);
#pragma unroll
    for (int m = 0; m < 4; ++m) aF[m] = lds_ld(la + arowb + m * 2048 + fb0);
    if (st) {   // stage tile u+1 (6 loads)
      gload16(pB + kn,                     nb + ldsbase);
      gload16(pB + (size_t) 64 * DIM + kn, nb +     8192 + ldsbase);
      gload16(pB + (size_t)128 * DIM + kn, nb + 2 * 8192 + ldsbase);
      gload16(pB + (size_t)192 * DIM + kn, nb + 3 * 8192 + ldsbase);
      gload16(pA + kn,                     na + ldsbase);
      gload16(pA + (size_t) 64 * DIM + kn, na +     8192 + ldsbase);
    }
    __builtin_amdgcn_s_barrier();
    asm volatile("s_waitcnt lgkmcnt(0)" ::: "memory");
    __builtin_amdgcn_s_setprio(1);
#pragma unroll
    for (int m = 0; m < 4; ++m)
#pragma unroll
      for (int n = 0; n < 4; ++n)
        acc[m][n] = __builtin_amdgcn_mfma_f32_16x16x32_bf16(aF[m], bF[n], acc[m][n], 0, 0, 0);
    __builtin_amdgcn_s_setprio(0);
    __builtin_amdgcn_s_barrier();

    // ---------------- phase 1: k-chunk 1 ----------------
#pragma unroll
    for (int n = 0; n < 4; ++n) bF[n] = lds_ld(lb + browb + n * 2048 + fb1);
#pragma unroll
    for (int m = 0; m < 4; ++m) aF[m] = lds_ld(la + arowb + m * 2048 + fb1);
    __builtin_amdgcn_s_barrier();
    asm volatile("s_waitcnt lgkmcnt(0)" ::: "memory");
    __builtin_amdgcn_s_setprio(1);
#pragma unroll
    for (int m = 0; m < 4; ++m)
#pragma unroll
      for (int n = 0; n < 4; ++n)
        acc[m][n] = __builtin_amdgcn_mfma_f32_16x16x32_bf16(aF[m], bF[n], acc[m][n], 0, 0, 0);
    __builtin_amdgcn_s_setprio(0);
    // staged loads were issued early in phase 0 -> drain is cheap here
    asm volatile("s_waitcnt vmcnt(0)" ::: "memory");
    __builtin_amdgcn_s_barrier();
  }

  // ---------------- epilogue: diag + per-row LSE partials ----------------
  __syncthreads();

  const int dof = i0 - j0;   // diagonal's column offset within this block
  if (dof >= 0 && dof < 256) {
#pragma unroll
    for (int m = 0; m < 4; ++m)
#pragma unroll
      for (int n = 0; n < 4; ++n)
#pragma unroll
        for (int rr = 0; rr < 4; ++rr) {
          const int rl = wm * 64 + m * 16 + (hi << 2) + rr;   // 0..127
          const int cl = wn * 64 + n * 16 + lr;               // 0..255
          if (cl == rl + dof) cstore(&diag[i0 + rl], acc[m][n][rr]);
        }
  }

  float* redm = (float*)smem;            // [4][128]
  float* reds = (float*)(smem + 2048);   // [4][128]

#pragma unroll
  for (int m = 0; m < 4; ++m) {
    float mx[4], sm[4];
#pragma unroll
    for (int rr = 0; rr < 4; ++rr) {
      float v = fmaxf(fmaxf(acc[m][0][rr], acc[m][1][rr]),
                      fmaxf(acc[m][2][rr], acc[m][3][rr]));
      mx[rr] = v;
    }
#pragma unroll
    for (int sh = 1; sh < 16; sh <<= 1)
#pragma unroll
      for (int rr = 0; rr < 4; ++rr)
        mx[rr] = fmaxf(mx[rr], __shfl_xor(mx[rr], sh, 64));
#pragma unroll
    for (int rr = 0; rr < 4; ++rr) {
      float s = 0.f;
#pragma unroll
      for (int n = 0; n < 4; ++n) s += __expf(acc[m][n][rr] - mx[rr]);
      sm[rr] = s;
    }
#pragma unroll
    for (int sh = 1; sh < 16; sh <<= 1)
#pragma unroll
      for (int rr = 0; rr < 4; ++rr)
        sm[rr] += __shfl_xor(sm[rr], sh, 64);
    if (lr == 0) {
#pragma unroll
      for (int rr = 0; rr < 4; ++rr) {
        const int rl = wm * 64 + m * 16 + (hi << 2) + rr;
        redm[(wn << 7) + rl] = mx[rr];
        reds[(wn << 7) + rl] = sm[rr];
      }
    }
  }
  __syncthreads();

  if (tid < 128) {
    float m = redm[tid];
#pragma unroll
    for (int v = 1; v < 4; ++v) m = fmaxf(m, redm[(v << 7) + tid]);
    float s = 0.f;
#pragma unroll
    for (int v = 0; v < 4; ++v) s += reds[(v << 7) + tid] * __expf(redm[(v << 7) + tid] - m);
    cstore(&pm[(size_t)by * BSZ + i0 + tid], m);
    cstore(&ps[(size_t)by * BSZ + i0 + tid], s);
  }

  // ---------------- cross-block merge (split-K last-block-wins) ----------------
  // All communicated stores above are sc1 (agent-coherent, past the XCD L2).
  // Each wave drains its own stores (vmcnt(0)), barrier, then one relaxed bump.
  asm volatile("s_waitcnt vmcnt(0)" ::: "memory");
  __syncthreads();
  __shared__ unsigned int sord;
  if (tid == 0) sord = atomicAdd(&cnt[bx], 1u);
  __syncthreads();
  if (sord == CSPLIT - 1) {
    float val = 0.f;
    if (tid < 128) {
      const int row = i0 + tid;
      float mv[CSPLIT];
      float m = -INFINITY;
#pragma unroll
      for (int c = 0; c < CSPLIT; ++c) {
        mv[c] = cload(&pm[(size_t)c * BSZ + row]);
        m = fmaxf(m, mv[c]);
      }
      float s = 0.f;
#pragma unroll
      for (int c = 0; c < CSPLIT; ++c)
        s += cload(&ps[(size_t)c * BSZ + row]) * __expf(mv[c] - m);
      val = (m + __logf(s)) - cload(&diag[row]);
    }
    float* red2 = (float*)smem;   // [512]; prior smem uses are done (synced above)
    red2[tid] = val;
    __syncthreads();
    for (int off = 256; off > 0; off >>= 1) {
      if (tid < off) red2[tid] += red2[tid + off];
      __syncthreads();
    }
    if (tid == 0) {
      cstore(&partial[bx], red2[0]);
      asm volatile("s_waitcnt vmcnt(0)" ::: "memory");
      unsigned int d = atomicAdd(&cnt[NPANEL], 1u);
      if (d == NPANEL - 1) {
        float s = 0.f;
        for (int i = 0; i < NPANEL; ++i) s += cload(&partial[i]);
        out[0] = s / (float)BSZ;
      }
    }
  }
}

extern "C" void kernel_launch(void* const* d_in, const int* in_sizes, int n_in,
                              void* d_out, int out_size, void* d_ws, size_t ws_size,
                              hipStream_t stream) {
  const float* code = (const float*)d_in[0];   // [BSZ][DIM]
  const float* nl   = (const float*)d_in[1];   // [BSZ][DIM]
  float* out = (float*)d_out;

  char* ws = (char*)d_ws;
  unsigned short* Abf = (unsigned short*)ws;                              // nl bf16
  unsigned short* Bbf = (unsigned short*)(ws + (size_t)BSZ * DIM * 2);    // code bf16
  float* pm   = (float*)(ws + (size_t)BSZ * DIM * 4);                     // [CSPLIT][BSZ]
  float* ps   = pm + (size_t)CSPLIT * BSZ;
  float* diag = ps + (size_t)CSPLIT * BSZ;                                // [BSZ]
  float* partial = diag + BSZ;                                            // [32]
  unsigned int* cnt = (unsigned int*)(partial + NPANEL);                  // [33]

  const int n4 = (BSZ * DIM) / 4;
  convert_kernel<<<(2 * n4) / 256, 256, 0, stream>>>(nl, code, Abf, Bbf, cnt);

  dim3 grid(BSZ / 128, BSZ / 256);
  gemm_lse_kernel<<<grid, 512, 0, stream>>>(Abf, Bbf, pm, ps, diag, partial, cnt, out);
}